// Round 1
// baseline (101.238 us; speedup 1.0000x reference)
//
#include <hip/hip_runtime.h>
#include <math.h>

#define RATE 0.1f
#define INV_KEEP (1.0f / 0.9f)
#define EPS 1e-4f
#define CLIP_MAG 8.0f
#define ACOSH_MIN 1.0001f

// One wave (64 lanes) per row of 512 floats: 2 float4 loads per lane per input.
// Everything stays in registers; single global pass.
__global__ __launch_bounds__(256) void hyp_dropout_kernel(
    const float* __restrict__ vecs,
    const float* __restrict__ curv,
    const float* __restrict__ mask,
    float* __restrict__ out,
    int nrows)
{
    const int wave = blockIdx.x * 4 + (threadIdx.x >> 6);
    const int lane = threadIdx.x & 63;
    if (wave >= nrows) return;

    const size_t base = (size_t)wave * 512;
    const float4* vr = (const float4*)(vecs + base);
    const float4* mr = (const float4*)(mask + base);

    float4 va = vr[lane];
    float4 vb = vr[lane + 64];
    float4 ma = mr[lane];
    float4 mb = mr[lane + 64];

    // keep flags (coordinate 0 is excluded from everything downstream)
    const float ka0 = (ma.x >= RATE) ? 1.f : 0.f;
    const float ka1 = (ma.y >= RATE) ? 1.f : 0.f;
    const float ka2 = (ma.z >= RATE) ? 1.f : 0.f;
    const float ka3 = (ma.w >= RATE) ? 1.f : 0.f;
    const float kb0 = (mb.x >= RATE) ? 1.f : 0.f;
    const float kb1 = (mb.y >= RATE) ? 1.f : 0.f;
    const float kb2 = (mb.z >= RATE) ? 1.f : 0.f;
    const float kb3 = (mb.w >= RATE) ? 1.f : 0.f;

    // coordinate 0 (lane 0, va.x) is dropped by _proj: zero it for the sums
    const float a0 = (lane == 0) ? 0.f : va.x;

    // s2 = sum x_j^2 (j>=1), m2 = sum keep_j * x_j^2 (j>=1)
    float s2 = a0 * a0;
    float m2 = ka0 * a0 * a0;
    s2 = fmaf(va.y, va.y, s2); m2 = fmaf(ka1 * va.y, va.y, m2);
    s2 = fmaf(va.z, va.z, s2); m2 = fmaf(ka2 * va.z, va.z, m2);
    s2 = fmaf(va.w, va.w, s2); m2 = fmaf(ka3 * va.w, va.w, m2);
    s2 = fmaf(vb.x, vb.x, s2); m2 = fmaf(kb0 * vb.x, vb.x, m2);
    s2 = fmaf(vb.y, vb.y, s2); m2 = fmaf(kb1 * vb.y, vb.y, m2);
    s2 = fmaf(vb.z, vb.z, s2); m2 = fmaf(kb2 * vb.z, vb.z, m2);
    s2 = fmaf(vb.w, vb.w, s2); m2 = fmaf(kb3 * vb.w, vb.w, m2);

    // 64-lane butterfly reduction of both sums (independent -> ILP)
    #pragma unroll
    for (int off = 32; off > 0; off >>= 1) {
        s2 += __shfl_xor(s2, off, 64);
        m2 += __shfl_xor(m2, off, 64);
    }

    const float c = curv[0];
    const float sqrt_c = sqrtf(c);

    // logmap scalars
    const float v0 = sqrtf(c + s2);                       // projected first coord
    const float arg = fmaxf(v0 / sqrt_c - EPS, ACOSH_MIN);
    const float dist = sqrt_c * acoshf(arg);
    const float scale1 = dist / (sqrtf(s2) + EPS);        // dist / (||unnorm||_H + eps)
    const float k = scale1 * INV_KEEP;                    // includes dropout 1/(1-rate)

    // expmap scalars; k >= 0 so ||dropped|| = k * sqrt(m2)
    const float sn = k * sqrtf(m2);
    const float snv = sn / sqrt_c + EPS;
    const float snv_c = fminf(fmaxf(snv, -CLIP_MAG), CLIP_MAG);
    const float sh = sinhf(snv_c) / snv;                  // coefficient for dropped[j]
    const float ch = coshf(snv_c) * sqrt_c;               // output coordinate 0

    // out[j] = sh * k * keep_j * x_j  (j>=1);  out[0] = ch
    const float w = sh * k;
    float4 oa, ob;
    oa.x = (lane == 0) ? ch : w * ka0 * va.x;
    oa.y = w * ka1 * va.y;
    oa.z = w * ka2 * va.z;
    oa.w = w * ka3 * va.w;
    ob.x = w * kb0 * vb.x;
    ob.y = w * kb1 * vb.y;
    ob.z = w * kb2 * vb.z;
    ob.w = w * kb3 * vb.w;

    float4* orow = (float4*)(out + base);
    orow[lane] = oa;
    orow[lane + 64] = ob;
}

extern "C" void kernel_launch(void* const* d_in, const int* in_sizes, int n_in,
                              void* d_out, int out_size, void* d_ws, size_t ws_size,
                              hipStream_t stream) {
    const float* vecs = (const float*)d_in[0];
    const float* curv = (const float*)d_in[1];
    const float* mask = (const float*)d_in[2];
    float* out = (float*)d_out;

    const int nrows = in_sizes[0] / 512;          // 16384
    const int waves_per_block = 4;                // 256 threads
    const int grid = (nrows + waves_per_block - 1) / waves_per_block;

    hyp_dropout_kernel<<<grid, 256, 0, stream>>>(vecs, curv, mask, out, nrows);
}